// Round 10
// baseline (509.071 us; speedup 1.0000x reference)
//
#include <hip/hip_runtime.h>
#include <hip/hip_bf16.h>

#define EDGE_DIM 64
#define UPD 256

typedef __attribute__((ext_vector_type(8))) short bf16x8;
typedef __attribute__((ext_vector_type(4))) float f32x4;

__device__ __forceinline__ short f2bf(float v) {
    __hip_bfloat16 b = __float2bfloat16(v);
    return *(short*)&b;
}
__device__ __forceinline__ float bf2f(short s) {
    __hip_bfloat16 b = *(__hip_bfloat16*)&s;
    return __bfloat162float(b);
}

// ---------------------------------------------------------------------------
// Per-block idx-dtype detection (deterministic across blocks).
// ---------------------------------------------------------------------------
__device__ __forceinline__ int detect_use64_block(const void* idx_v,
                                                  int n_edge, int nn,
                                                  int* bad_s) {
    if (threadIdx.x == 0) *bad_s = 0;
    __syncthreads();
    const long long* p = (const long long*)idx_v;
    int i = threadIdx.x;
    if (i < 256 && i < n_edge) {
        long long v = p[i];
        if (v < 0 || v >= (long long)nn) *bad_s = 1;  // benign race
    }
    __syncthreads();
    return !(*bad_s);
}

// ---------------------------------------------------------------------------
// Counting sort phase A: per-node histogram.
// ---------------------------------------------------------------------------
__global__ __launch_bounds__(256) void count_kernel(
    const void* __restrict__ idx_v, int n_edge, int nn,
    int* __restrict__ count) {
    __shared__ int bad_s;
    const int use64 = detect_use64_block(idx_v, n_edge, nn, &bad_s);
    const long long* i64 = (const long long*)idx_v;
    const int* i32 = (const int*)idx_v;
    for (int e = blockIdx.x * blockDim.x + threadIdx.x; e < n_edge;
         e += gridDim.x * blockDim.x) {
        int n = use64 ? (int)i64[e] : i32[e];
        atomicAdd(&count[n], 1);
    }
}

// ---------------------------------------------------------------------------
// Exclusive scan over count[nn] -> base[nn+1]  (3 kernels).
// ---------------------------------------------------------------------------
__global__ __launch_bounds__(256) void scan_a(const int* __restrict__ count,
                                              int* __restrict__ base,
                                              int* __restrict__ partial,
                                              int nn) {
    __shared__ int s[256];
    const int tid = threadIdx.x;
    const int i0 = blockIdx.x * 1024 + tid * 4;
    int c[4], tsum = 0;
#pragma unroll
    for (int j = 0; j < 4; ++j) {
        c[j] = (i0 + j < nn) ? count[i0 + j] : 0;
        tsum += c[j];
    }
    s[tid] = tsum;
    __syncthreads();
    for (int off = 1; off < 256; off <<= 1) {
        int v = (tid >= off) ? s[tid - off] : 0;
        __syncthreads();
        s[tid] += v;
        __syncthreads();
    }
    int run = s[tid] - tsum;
    if (tid == 255) partial[blockIdx.x] = s[255];
#pragma unroll
    for (int j = 0; j < 4; ++j) {
        if (i0 + j < nn) base[i0 + j] = run;
        run += c[j];
    }
}

__global__ __launch_bounds__(256) void scan_b(int* __restrict__ partial,
                                              int nblk) {
    __shared__ int s[256];
    const int tid = threadIdx.x;
    int v = (tid < nblk) ? partial[tid] : 0;
    s[tid] = v;
    __syncthreads();
    for (int off = 1; off < 256; off <<= 1) {
        int u = (tid >= off) ? s[tid - off] : 0;
        __syncthreads();
        s[tid] += u;
        __syncthreads();
    }
    if (tid < nblk) partial[tid] = s[tid] - v;
}

__global__ __launch_bounds__(256) void scan_c(int* __restrict__ base,
                                              int* __restrict__ cursor,
                                              const int* __restrict__ partial,
                                              int nn, int n_edge) {
    const int tid = threadIdx.x;
    const int b = blockIdx.x;
    const int add = partial[b];
    const int i0 = b * 1024 + tid * 4;
#pragma unroll
    for (int j = 0; j < 4; ++j) {
        int i = i0 + j;
        if (i < nn) {
            int v = base[i] + add;
            base[i] = v;
            cursor[i] = v;
        }
    }
    if (b == 0 && tid == 0) base[nn] = n_edge;
}

// ---------------------------------------------------------------------------
// Phase B: slot[e] = destination position of edge e in node-sorted order.
// ---------------------------------------------------------------------------
__global__ __launch_bounds__(256) void fill_slot_kernel(
    const void* __restrict__ idx_v, int n_edge, int nn,
    int* __restrict__ cursor, int* __restrict__ slot) {
    __shared__ int bad_s;
    const int use64 = detect_use64_block(idx_v, n_edge, nn, &bad_s);
    const long long* i64 = (const long long*)idx_v;
    const int* i32 = (const int*)idx_v;
    for (int e = blockIdx.x * blockDim.x + threadIdx.x; e < n_edge;
         e += gridDim.x * blockDim.x) {
        int n = use64 ? (int)i64[e] : i32[e];
        slot[e] = atomicAdd(&cursor[n], 1);
    }
}

// ---------------------------------------------------------------------------
// Phase C: streaming gate + scatter-STORE. Edges in ORIGINAL order:
// x reads affine+coalesced, rbf/slot wave-uniform scalar loads, y row
// stored as 128B coalesced bf16 line at slot[e]. NO load depends on a load;
// stores are fire-and-forget -> fully pipelined streaming.
// ---------------------------------------------------------------------------
__global__ __launch_bounds__(256) void scatter_y_kernel(
    const float* __restrict__ x, const float* __restrict__ rbf,
    const int* __restrict__ slot, const float* __restrict__ Wrbf,
    __hip_bfloat16* __restrict__ y, int n_edge) {
    const int lane = threadIdx.x & 63;
    float wreg[16];
#pragma unroll
    for (int q = 0; q < 16; ++q) wreg[q] = Wrbf[q * EDGE_DIM + lane];

    const int wid = threadIdx.x >> 6;  // wave-uniform
    const int gw = blockIdx.x * 4 + wid;
    const int nwaves = gridDim.x * 4;

    int e0 = gw * 4;
    for (; e0 + 4 <= n_edge; e0 += nwaves * 4) {
        const int s0 = slot[e0 + 0];  // uniform address -> s_load
        const int s1 = slot[e0 + 1];
        const int s2 = slot[e0 + 2];
        const int s3 = slot[e0 + 3];
        const float xv0 = x[(size_t)(e0 + 0) * EDGE_DIM + lane];
        const float xv1 = x[(size_t)(e0 + 1) * EDGE_DIM + lane];
        const float xv2 = x[(size_t)(e0 + 2) * EDGE_DIM + lane];
        const float xv3 = x[(size_t)(e0 + 3) * EDGE_DIM + lane];
        const float* r0 = rbf + (size_t)(e0 + 0) * 16;  // uniform -> scalar
        const float* r1 = rbf + (size_t)(e0 + 1) * 16;
        const float* r2 = rbf + (size_t)(e0 + 2) * 16;
        const float* r3 = rbf + (size_t)(e0 + 3) * 16;
        float g0 = 0.f, g1 = 0.f, g2 = 0.f, g3 = 0.f;
#pragma unroll
        for (int q = 0; q < 16; ++q) {
            g0 = fmaf(r0[q], wreg[q], g0);
            g1 = fmaf(r1[q], wreg[q], g1);
            g2 = fmaf(r2[q], wreg[q], g2);
            g3 = fmaf(r3[q], wreg[q], g3);
        }
        y[(size_t)s0 * EDGE_DIM + lane] = __float2bfloat16(g0 * xv0);
        y[(size_t)s1 * EDGE_DIM + lane] = __float2bfloat16(g1 * xv1);
        y[(size_t)s2 * EDGE_DIM + lane] = __float2bfloat16(g2 * xv2);
        y[(size_t)s3 * EDGE_DIM + lane] = __float2bfloat16(g3 * xv3);
    }
    // Tail (n_edge % 4), one wave handles it.
    if (gw == 0) {
        for (int e = n_edge & ~3; e < n_edge; ++e) {
            const int sl = slot[e];
            const float xv = x[(size_t)e * EDGE_DIM + lane];
            const float* rp = rbf + (size_t)e * 16;
            float g = 0.f;
#pragma unroll
            for (int q = 0; q < 16; ++q) g = fmaf(rp[q], wreg[q], g);
            y[(size_t)sl * EDGE_DIM + lane] = __float2bfloat16(g * xv);
        }
    }
}

// ---------------------------------------------------------------------------
// Pack all 4 weight matrices into MFMA-fragment bf16 hi/lo order.
// ---------------------------------------------------------------------------
__device__ __forceinline__ void pack_body(const float* __restrict__ W,
                                          short* __restrict__ out, int t) {
    int l = t & 63, f = t >> 6;
    int kt = f >> 4, nt = f & 15;
    int kbase = kt * 32 + (l >> 4) * 8;
    int col = nt * 16 + (l & 15);
#pragma unroll
    for (int j = 0; j < 8; ++j) {
        float v = W[(kbase + j) * UPD + col];
        short hb = f2bf(v);
        short lb = f2bf(v - bf2f(hb));
        out[f * 1024 + l * 8 + j] = hb;
        out[f * 1024 + 512 + l * 8 + j] = lb;
    }
}

__global__ __launch_bounds__(256) void pack_all_kernel(
    const float* __restrict__ Wup, const float* __restrict__ W1,
    const float* __restrict__ W2, const float* __restrict__ W3,
    short* __restrict__ oup, short* __restrict__ o1, short* __restrict__ o2,
    short* __restrict__ o3) {
    const int b = blockIdx.x;
    if (b < 8) {
        pack_body(Wup, oup, b * 256 + threadIdx.x);
    } else if (b < 40) {
        pack_body(W1, o1, (b - 8) * 256 + threadIdx.x);
    } else if (b < 72) {
        pack_body(W2, o2, (b - 40) * 256 + threadIdx.x);
    } else {
        pack_body(W3, o3, (b - 72) * 256 + threadIdx.x);
    }
}

// ---------------------------------------------------------------------------
// MFMA node MLP with fused, PARALLEL y-reduction staging:
// 4 threads per node, 16 dims each; y addresses are affine (sorted rows),
// 4x16B independent loads per 2-step unroll; f32 accumulate -> hi/lo LDS.
// ---------------------------------------------------------------------------
template <int NK>
__device__ __forceinline__ void mm_layer(const short* AH, const short* AL,
                                         const short* __restrict__ Wpk,
                                         int lr, int lh, int lane, int wq,
                                         f32x4 acc[4][4]) {
#pragma unroll
    for (int kt = 0; kt < NK; ++kt) {
        bf16x8 a[4][2];
#pragma unroll
        for (int m = 0; m < 4; ++m) {
            int r = m * 16 + lr;
            int ch = (kt * 4 + lh) ^ (r & 7);
            int off = r * 256 + ch * 8;  // shorts
            a[m][0] = *(const bf16x8*)(AH + off);
            a[m][1] = *(const bf16x8*)(AL + off);
        }
        bf16x8 b[4][2];
#pragma unroll
        for (int nf = 0; nf < 4; ++nf) {
            int f = kt * 16 + wq * 4 + nf;
            const short* p = Wpk + f * 1024 + lane * 8;
            b[nf][0] = *(const bf16x8*)(p);
            b[nf][1] = *(const bf16x8*)(p + 512);
        }
#pragma unroll
        for (int m = 0; m < 4; ++m)
#pragma unroll
            for (int nf = 0; nf < 4; ++nf)
                acc[m][nf] = __builtin_amdgcn_mfma_f32_16x16x32_bf16(
                    a[m][0], b[nf][0], acc[m][nf], 0, 0, 0);
#pragma unroll
        for (int m = 0; m < 4; ++m)
#pragma unroll
            for (int nf = 0; nf < 4; ++nf)
                acc[m][nf] = __builtin_amdgcn_mfma_f32_16x16x32_bf16(
                    a[m][0], b[nf][1], acc[m][nf], 0, 0, 0);
#pragma unroll
        for (int m = 0; m < 4; ++m)
#pragma unroll
            for (int nf = 0; nf < 4; ++nf)
                acc[m][nf] = __builtin_amdgcn_mfma_f32_16x16x32_bf16(
                    a[m][1], b[nf][0], acc[m][nf], 0, 0, 0);
    }
}

template <bool ACT>
__device__ __forceinline__ void epilogue_store(f32x4 acc[4][4], short* AH,
                                               short* AL,
                                               const float* __restrict__ bias,
                                               int lr, int lh, int wq) {
    float bv[4] = {0.f, 0.f, 0.f, 0.f};
    if (bias) {
#pragma unroll
        for (int nf = 0; nf < 4; ++nf) bv[nf] = bias[wq * 64 + nf * 16 + lr];
    }
#pragma unroll
    for (int m = 0; m < 4; ++m)
#pragma unroll
        for (int nf = 0; nf < 4; ++nf) {
            int c = wq * 64 + nf * 16 + lr;
#pragma unroll
            for (int reg = 0; reg < 4; ++reg) {
                float v = acc[m][nf][reg] + bv[nf];
                if (ACT) v = v / (1.f + __expf(-v));
                int r = m * 16 + lh * 4 + reg;
                short hb = f2bf(v);
                short lb = f2bf(v - bf2f(hb));
                int off = r * 256 + (((c >> 3) ^ (r & 7)) * 8) + (c & 7);
                AH[off] = hb;
                AL[off] = lb;
            }
        }
}

__device__ __forceinline__ uint4 pack8(const short* v) {
    uint4 u;
    u.x = (unsigned short)v[0] | ((unsigned)(unsigned short)v[1] << 16);
    u.y = (unsigned short)v[2] | ((unsigned)(unsigned short)v[3] << 16);
    u.z = (unsigned short)v[4] | ((unsigned)(unsigned short)v[5] << 16);
    u.w = (unsigned short)v[6] | ((unsigned)(unsigned short)v[7] << 16);
    return u;
}

__global__ __launch_bounds__(256, 2) void node_mlp_mfma(
    const __hip_bfloat16* __restrict__ y, const int* __restrict__ base,
    const short* __restrict__ Wup_pk, const short* __restrict__ W1_pk,
    const short* __restrict__ W2_pk, const short* __restrict__ W3_pk,
    const float* __restrict__ b1, const float* __restrict__ b2,
    const float* __restrict__ b3, const float* __restrict__ W_out,
    float* __restrict__ out, int nn) {
    __shared__ short AH[64 * 256];
    __shared__ short AL[64 * 256];
    __shared__ float Bpart[64 * 4];

    const int tid = threadIdx.x;
    const int lane = tid & 63, wq = tid >> 6;
    const int lr = lane & 15, lh = lane >> 4;
    const int node0 = blockIdx.x * 64;

    // ---- fused segment-sum staging: thread t -> node r=t>>2, dims dq..dq+15
    {
        const int r = tid >> 2;
        const int dq = (tid & 3) << 4;
        const int n = node0 + r;
        float acc[16];
#pragma unroll
        for (int k = 0; k < 16; ++k) acc[k] = 0.f;
        if (n < nn) {
            const int b0 = base[n], b1v = base[n + 1];
            const ushort* yp = (const ushort*)y;
            int s = b0;
            for (; s + 2 <= b1v; s += 2) {
                uint4 va0 = *(const uint4*)(yp + (size_t)(s + 0) * EDGE_DIM + dq);
                uint4 va1 = *(const uint4*)(yp + (size_t)(s + 0) * EDGE_DIM + dq + 8);
                uint4 vb0 = *(const uint4*)(yp + (size_t)(s + 1) * EDGE_DIM + dq);
                uint4 vb1 = *(const uint4*)(yp + (size_t)(s + 1) * EDGE_DIM + dq + 8);
                const ushort* a0 = (const ushort*)&va0;
                const ushort* a1 = (const ushort*)&va1;
                const ushort* c0 = (const ushort*)&vb0;
                const ushort* c1 = (const ushort*)&vb1;
#pragma unroll
                for (int k = 0; k < 8; ++k) {
                    acc[k] += bf2f((short)a0[k]) + bf2f((short)c0[k]);
                    acc[8 + k] += bf2f((short)a1[k]) + bf2f((short)c1[k]);
                }
            }
            for (; s < b1v; ++s) {
                uint4 va0 = *(const uint4*)(yp + (size_t)s * EDGE_DIM + dq);
                uint4 va1 = *(const uint4*)(yp + (size_t)s * EDGE_DIM + dq + 8);
                const ushort* a0 = (const ushort*)&va0;
                const ushort* a1 = (const ushort*)&va1;
#pragma unroll
                for (int k = 0; k < 8; ++k) {
                    acc[k] += bf2f((short)a0[k]);
                    acc[8 + k] += bf2f((short)a1[k]);
                }
            }
        }
        short hbuf[16], lbuf[16];
#pragma unroll
        for (int k = 0; k < 16; ++k) {
            hbuf[k] = f2bf(acc[k]);
            lbuf[k] = f2bf(acc[k] - bf2f(hbuf[k]));
        }
        const int cc0 = dq >> 3;  // logical 8-col chunk
        const int ph0 = (cc0 ^ (r & 7)) * 8;
        const int ph1 = ((cc0 + 1) ^ (r & 7)) * 8;
        *(uint4*)(AH + r * 256 + ph0) = pack8(hbuf);
        *(uint4*)(AH + r * 256 + ph1) = pack8(hbuf + 8);
        *(uint4*)(AL + r * 256 + ph0) = pack8(lbuf);
        *(uint4*)(AL + r * 256 + ph1) = pack8(lbuf + 8);
    }
    __syncthreads();

    f32x4 acc[4][4];

#pragma unroll
    for (int m = 0; m < 4; ++m)
#pragma unroll
        for (int n = 0; n < 4; ++n) acc[m][n] = (f32x4){0.f, 0.f, 0.f, 0.f};
    mm_layer<2>(AH, AL, Wup_pk, lr, lh, lane, wq, acc);
    __syncthreads();
    epilogue_store<false>(acc, AH, AL, nullptr, lr, lh, wq);
    __syncthreads();

#pragma unroll
    for (int m = 0; m < 4; ++m)
#pragma unroll
        for (int n = 0; n < 4; ++n) acc[m][n] = (f32x4){0.f, 0.f, 0.f, 0.f};
    mm_layer<8>(AH, AL, W1_pk, lr, lh, lane, wq, acc);
    __syncthreads();
    epilogue_store<true>(acc, AH, AL, b1, lr, lh, wq);
    __syncthreads();

#pragma unroll
    for (int m = 0; m < 4; ++m)
#pragma unroll
        for (int n = 0; n < 4; ++n) acc[m][n] = (f32x4){0.f, 0.f, 0.f, 0.f};
    mm_layer<8>(AH, AL, W2_pk, lr, lh, lane, wq, acc);
    __syncthreads();
    epilogue_store<true>(acc, AH, AL, b2, lr, lh, wq);
    __syncthreads();

#pragma unroll
    for (int m = 0; m < 4; ++m)
#pragma unroll
        for (int n = 0; n < 4; ++n) acc[m][n] = (f32x4){0.f, 0.f, 0.f, 0.f};
    mm_layer<8>(AH, AL, W3_pk, lr, lh, lane, wq, acc);

    float b3v[4], wo[4];
#pragma unroll
    for (int nf = 0; nf < 4; ++nf) {
        int c = wq * 64 + nf * 16 + lr;
        b3v[nf] = b3[c];
        wo[nf] = W_out[c];
    }
#pragma unroll
    for (int m = 0; m < 4; ++m) {
#pragma unroll
        for (int reg = 0; reg < 4; ++reg) {
            float s = 0.f;
#pragma unroll
            for (int nf = 0; nf < 4; ++nf) {
                float v = acc[m][nf][reg] + b3v[nf];
                v = v / (1.f + __expf(-v));
                s = fmaf(v, wo[nf], s);
            }
            s += __shfl_xor(s, 1);
            s += __shfl_xor(s, 2);
            s += __shfl_xor(s, 4);
            s += __shfl_xor(s, 8);
            if (lr == 0) Bpart[(m * 16 + lh * 4 + reg) * 4 + wq] = s;
        }
    }
    __syncthreads();
    if (tid < 64) {
        float s = Bpart[tid * 4] + Bpart[tid * 4 + 1] + Bpart[tid * 4 + 2] +
                  Bpart[tid * 4 + 3];
        if (node0 + tid < nn) out[node0 + tid] = s;
    }
}

// ---------------------------------------------------------------------------
extern "C" void kernel_launch(void* const* d_in, const int* in_sizes, int n_in,
                              void* d_out, int out_size, void* d_ws, size_t ws_size,
                              hipStream_t stream) {
    const float* x     = (const float*)d_in[0];
    const float* rbf   = (const float*)d_in[1];
    const void*  idx   = d_in[2];
    const float* W_rbf = (const float*)d_in[4];
    const float* W_up  = (const float*)d_in[5];
    const float* W1    = (const float*)d_in[6];
    const float* b1    = (const float*)d_in[7];
    const float* W2    = (const float*)d_in[8];
    const float* b2    = (const float*)d_in[9];
    const float* W3    = (const float*)d_in[10];
    const float* b3    = (const float*)d_in[11];
    const float* W_out = (const float*)d_in[12];
    float* out = (float*)d_out;

    const int n_edge = in_sizes[0] / EDGE_DIM;
    const int nn = out_size;

    // Workspace layout
    char* p = (char*)d_ws;
    short* wup_pk = (short*)p;  p += (size_t)32 * 1024 * 2;
    short* w1_pk = (short*)p;   p += (size_t)128 * 1024 * 2;
    short* w2_pk = (short*)p;   p += (size_t)128 * 1024 * 2;
    short* w3_pk = (short*)p;   p += (size_t)128 * 1024 * 2;
    int* count = (int*)p;       p += (size_t)nn * 4;
    int* base = (int*)p;        p += (size_t)(nn + 1) * 4 + 12;  // keep 16B align
    int* cursor = (int*)p;      p += (size_t)nn * 4;
    int* partial = (int*)p;     p += 1024;
    int* slot = (int*)p;        p += (size_t)n_edge * 4;
    __hip_bfloat16* y = (__hip_bfloat16*)p;  // n_edge * 64 * 2 bytes

    const int nblk_scan = (nn + 1023) / 1024;

    hipMemsetAsync(count, 0, (size_t)nn * 4, stream);
    pack_all_kernel<<<104, 256, 0, stream>>>(W_up, W1, W2, W3, wup_pk, w1_pk,
                                             w2_pk, w3_pk);
    count_kernel<<<2048, 256, 0, stream>>>(idx, n_edge, nn, count);
    scan_a<<<nblk_scan, 256, 0, stream>>>(count, base, partial, nn);
    scan_b<<<1, 256, 0, stream>>>(partial, nblk_scan);
    scan_c<<<nblk_scan, 256, 0, stream>>>(base, cursor, partial, nn, n_edge);
    fill_slot_kernel<<<2048, 256, 0, stream>>>(idx, n_edge, nn, cursor, slot);
    scatter_y_kernel<<<4096, 256, 0, stream>>>(x, rbf, slot, W_rbf, y, n_edge);
    const int nb = (nn + 63) / 64;
    node_mlp_mfma<<<nb, 256, 0, stream>>>(y, base, wup_pk, w1_pk, w2_pk,
                                          w3_pk, b1, b2, b3, W_out, out, nn);
}

// Round 11
// 369.688 us; speedup vs baseline: 1.3770x; 1.3770x over previous
//
#include <hip/hip_runtime.h>
#include <hip/hip_bf16.h>

#define EDGE_DIM 64
#define UPD 256

typedef __attribute__((ext_vector_type(8))) short bf16x8;
typedef __attribute__((ext_vector_type(4))) float f32x4;

__device__ __forceinline__ short f2bf(float v) {
    __hip_bfloat16 b = __float2bfloat16(v);
    return *(short*)&b;
}
__device__ __forceinline__ float bf2f(short s) {
    __hip_bfloat16 b = *(__hip_bfloat16*)&s;
    return __bfloat162float(b);
}

// Cheap truncation hi/lo split: hi = upper 16 bits of v (exact float),
// lo = trunc16(v - hi). ~5 VALU ops vs ~14 for the RNE dance; combined
// representation error ~2^-17 relative (lo captures remainder exactly).
__device__ __forceinline__ void split_trunc(float v, short& hi, short& lo) {
    unsigned u = __float_as_uint(v);
    unsigned hu = u & 0xFFFF0000u;
    hi = (short)(hu >> 16);
    float rem = v - __uint_as_float(hu);
    lo = (short)(__float_as_uint(rem) >> 16);
}

// ---------------------------------------------------------------------------
// Per-block idx-dtype detection (deterministic across blocks).
// ---------------------------------------------------------------------------
__device__ __forceinline__ int detect_use64_block(const void* idx_v,
                                                  int n_edge, int nn,
                                                  int* bad_s) {
    if (threadIdx.x == 0) *bad_s = 0;
    __syncthreads();
    const long long* p = (const long long*)idx_v;
    int i = threadIdx.x;
    if (i < 256 && i < n_edge) {
        long long v = p[i];
        if (v < 0 || v >= (long long)nn) *bad_s = 1;  // benign race
    }
    __syncthreads();
    return !(*bad_s);
}

// ---------------------------------------------------------------------------
// Counting sort phase A: per-node histogram.
// ---------------------------------------------------------------------------
__global__ __launch_bounds__(256) void count_kernel(
    const void* __restrict__ idx_v, int n_edge, int nn,
    int* __restrict__ count) {
    __shared__ int bad_s;
    const int use64 = detect_use64_block(idx_v, n_edge, nn, &bad_s);
    const long long* i64 = (const long long*)idx_v;
    const int* i32 = (const int*)idx_v;
    for (int e = blockIdx.x * blockDim.x + threadIdx.x; e < n_edge;
         e += gridDim.x * blockDim.x) {
        int n = use64 ? (int)i64[e] : i32[e];
        atomicAdd(&count[n], 1);
    }
}

// ---------------------------------------------------------------------------
// Exclusive scan over count[nn] -> base[nn+1]  (3 kernels).
// ---------------------------------------------------------------------------
__global__ __launch_bounds__(256) void scan_a(const int* __restrict__ count,
                                              int* __restrict__ base,
                                              int* __restrict__ partial,
                                              int nn) {
    __shared__ int s[256];
    const int tid = threadIdx.x;
    const int i0 = blockIdx.x * 1024 + tid * 4;
    int c[4], tsum = 0;
#pragma unroll
    for (int j = 0; j < 4; ++j) {
        c[j] = (i0 + j < nn) ? count[i0 + j] : 0;
        tsum += c[j];
    }
    s[tid] = tsum;
    __syncthreads();
    for (int off = 1; off < 256; off <<= 1) {
        int v = (tid >= off) ? s[tid - off] : 0;
        __syncthreads();
        s[tid] += v;
        __syncthreads();
    }
    int run = s[tid] - tsum;
    if (tid == 255) partial[blockIdx.x] = s[255];
#pragma unroll
    for (int j = 0; j < 4; ++j) {
        if (i0 + j < nn) base[i0 + j] = run;
        run += c[j];
    }
}

__global__ __launch_bounds__(256) void scan_b(int* __restrict__ partial,
                                              int nblk) {
    __shared__ int s[256];
    const int tid = threadIdx.x;
    int v = (tid < nblk) ? partial[tid] : 0;
    s[tid] = v;
    __syncthreads();
    for (int off = 1; off < 256; off <<= 1) {
        int u = (tid >= off) ? s[tid - off] : 0;
        __syncthreads();
        s[tid] += u;
        __syncthreads();
    }
    if (tid < nblk) partial[tid] = s[tid] - v;
}

__global__ __launch_bounds__(256) void scan_c(int* __restrict__ base,
                                              int* __restrict__ cursor,
                                              const int* __restrict__ partial,
                                              int nn, int n_edge) {
    const int tid = threadIdx.x;
    const int b = blockIdx.x;
    const int add = partial[b];
    const int i0 = b * 1024 + tid * 4;
#pragma unroll
    for (int j = 0; j < 4; ++j) {
        int i = i0 + j;
        if (i < nn) {
            int v = base[i] + add;
            base[i] = v;
            cursor[i] = v;
        }
    }
    if (b == 0 && tid == 0) base[nn] = n_edge;
}

// ---------------------------------------------------------------------------
// Phase B: scatter edge ids into node-sorted slot order.
// ---------------------------------------------------------------------------
__global__ __launch_bounds__(256) void fill_order_kernel(
    const void* __restrict__ idx_v, int n_edge, int nn,
    int* __restrict__ cursor, int* __restrict__ order) {
    __shared__ int bad_s;
    const int use64 = detect_use64_block(idx_v, n_edge, nn, &bad_s);
    const long long* i64 = (const long long*)idx_v;
    const int* i32 = (const int*)idx_v;
    for (int e = blockIdx.x * blockDim.x + threadIdx.x; e < n_edge;
         e += gridDim.x * blockDim.x) {
        int n = use64 ? (int)i64[e] : i32[e];
        int p = atomicAdd(&cursor[n], 1);
        order[p] = e;
    }
}

// ---------------------------------------------------------------------------
// Phase C: per-node gather-reduce (R4 version — best measured: 164us).
// Scalarized walk (wave-uniform node) + 4-edge unroll.
// ---------------------------------------------------------------------------
__global__ __launch_bounds__(256) void gather_kernel(
    const float* __restrict__ x, const float* __restrict__ rbf,
    const int* __restrict__ order, const int* __restrict__ base,
    const float* __restrict__ Wrbf, float* __restrict__ h, int nn) {
    const int lane = threadIdx.x & 63;
    float wreg[16];
#pragma unroll
    for (int q = 0; q < 16; ++q) wreg[q] = Wrbf[q * EDGE_DIM + lane];

    const int wid = __builtin_amdgcn_readfirstlane(threadIdx.x >> 6);
    const int gw = blockIdx.x * 4 + wid;
    const int nwaves = gridDim.x * 4;

    for (int n = gw; n < nn; n += nwaves) {
        const int b0 = base[n], b1 = base[n + 1];
        float acc = 0.f;
        int i = b0;
        for (; i + 4 <= b1; i += 4) {
            const int e0 = order[i + 0];
            const int e1 = order[i + 1];
            const int e2 = order[i + 2];
            const int e3 = order[i + 3];
            const float xv0 = x[(size_t)e0 * EDGE_DIM + lane];
            const float xv1 = x[(size_t)e1 * EDGE_DIM + lane];
            const float xv2 = x[(size_t)e2 * EDGE_DIM + lane];
            const float xv3 = x[(size_t)e3 * EDGE_DIM + lane];
            const float* r0 = rbf + (size_t)e0 * 16;
            const float* r1 = rbf + (size_t)e1 * 16;
            const float* r2 = rbf + (size_t)e2 * 16;
            const float* r3 = rbf + (size_t)e3 * 16;
            float s0 = 0.f, s1 = 0.f, s2 = 0.f, s3 = 0.f;
#pragma unroll
            for (int q = 0; q < 16; ++q) {
                s0 = fmaf(r0[q], wreg[q], s0);
                s1 = fmaf(r1[q], wreg[q], s1);
                s2 = fmaf(r2[q], wreg[q], s2);
                s3 = fmaf(r3[q], wreg[q], s3);
            }
            acc = fmaf(s0, xv0, acc);
            acc = fmaf(s1, xv1, acc);
            acc = fmaf(s2, xv2, acc);
            acc = fmaf(s3, xv3, acc);
        }
        for (; i < b1; ++i) {
            const int e = order[i];
            const float xv = x[(size_t)e * EDGE_DIM + lane];
            const float* rp = rbf + (size_t)e * 16;
            float s = 0.f;
#pragma unroll
            for (int q = 0; q < 16; ++q) s = fmaf(rp[q], wreg[q], s);
            acc = fmaf(s, xv, acc);
        }
        h[(size_t)n * EDGE_DIM + lane] = acc;
    }
}

// ---------------------------------------------------------------------------
// Pack all 4 weight matrices into MFMA-fragment bf16 hi/lo order (RNE split
// is fine here; off critical path).
// ---------------------------------------------------------------------------
__device__ __forceinline__ void pack_body(const float* __restrict__ W,
                                          short* __restrict__ out, int t) {
    int l = t & 63, f = t >> 6;
    int kt = f >> 4, nt = f & 15;
    int kbase = kt * 32 + (l >> 4) * 8;
    int col = nt * 16 + (l & 15);
#pragma unroll
    for (int j = 0; j < 8; ++j) {
        float v = W[(kbase + j) * UPD + col];
        short hb = f2bf(v);
        short lb = f2bf(v - bf2f(hb));
        out[f * 1024 + l * 8 + j] = hb;
        out[f * 1024 + 512 + l * 8 + j] = lb;
    }
}

__global__ __launch_bounds__(256) void pack_all_kernel(
    const float* __restrict__ Wup, const float* __restrict__ W1,
    const float* __restrict__ W2, const float* __restrict__ W3,
    short* __restrict__ oup, short* __restrict__ o1, short* __restrict__ o2,
    short* __restrict__ o3) {
    const int b = blockIdx.x;
    if (b < 8) {
        pack_body(Wup, oup, b * 256 + threadIdx.x);
    } else if (b < 40) {
        pack_body(W1, o1, (b - 8) * 256 + threadIdx.x);
    } else if (b < 72) {
        pack_body(W2, o2, (b - 40) * 256 + threadIdx.x);
    } else {
        pack_body(W3, o3, (b - 72) * 256 + threadIdx.x);
    }
}

// ---------------------------------------------------------------------------
// MFMA node MLP. Changes vs R4:
//  - explicit one-kt-ahead B register prefetch (hide L2 latency at 2w/SIMD)
//  - truncation hi/lo split in staging + epilogue (~5 VALU vs ~14)
//  - cheap SiLU via rcpf
// ---------------------------------------------------------------------------
template <int NK>
__device__ __forceinline__ void mm_layer(const short* AH, const short* AL,
                                         const short* __restrict__ Wpk,
                                         int lr, int lh, int lane, int wq,
                                         f32x4 acc[4][4]) {
    bf16x8 bc[4][2];
#pragma unroll
    for (int nf = 0; nf < 4; ++nf) {
        const short* p = Wpk + (wq * 4 + nf) * 1024 + lane * 8;
        bc[nf][0] = *(const bf16x8*)(p);
        bc[nf][1] = *(const bf16x8*)(p + 512);
    }
#pragma unroll
    for (int kt = 0; kt < NK; ++kt) {
        bf16x8 a[4][2];
#pragma unroll
        for (int m = 0; m < 4; ++m) {
            int r = m * 16 + lr;
            int ch = (kt * 4 + lh) ^ (r & 7);
            int off = r * 256 + ch * 8;  // shorts
            a[m][0] = *(const bf16x8*)(AH + off);
            a[m][1] = *(const bf16x8*)(AL + off);
        }
        bf16x8 bn[4][2];
        if (kt + 1 < NK) {
#pragma unroll
            for (int nf = 0; nf < 4; ++nf) {
                const short* p =
                    Wpk + ((kt + 1) * 16 + wq * 4 + nf) * 1024 + lane * 8;
                bn[nf][0] = *(const bf16x8*)(p);
                bn[nf][1] = *(const bf16x8*)(p + 512);
            }
        }
#pragma unroll
        for (int m = 0; m < 4; ++m)
#pragma unroll
            for (int nf = 0; nf < 4; ++nf)
                acc[m][nf] = __builtin_amdgcn_mfma_f32_16x16x32_bf16(
                    a[m][0], bc[nf][0], acc[m][nf], 0, 0, 0);
#pragma unroll
        for (int m = 0; m < 4; ++m)
#pragma unroll
            for (int nf = 0; nf < 4; ++nf)
                acc[m][nf] = __builtin_amdgcn_mfma_f32_16x16x32_bf16(
                    a[m][0], bc[nf][1], acc[m][nf], 0, 0, 0);
#pragma unroll
        for (int m = 0; m < 4; ++m)
#pragma unroll
            for (int nf = 0; nf < 4; ++nf)
                acc[m][nf] = __builtin_amdgcn_mfma_f32_16x16x32_bf16(
                    a[m][1], bc[nf][0], acc[m][nf], 0, 0, 0);
        if (kt + 1 < NK) {
#pragma unroll
            for (int nf = 0; nf < 4; ++nf) {
                bc[nf][0] = bn[nf][0];
                bc[nf][1] = bn[nf][1];
            }
        }
    }
}

template <bool ACT>
__device__ __forceinline__ void epilogue_store(f32x4 acc[4][4], short* AH,
                                               short* AL,
                                               const float* __restrict__ bias,
                                               int lr, int lh, int wq) {
    float bv[4] = {0.f, 0.f, 0.f, 0.f};
    if (bias) {
#pragma unroll
        for (int nf = 0; nf < 4; ++nf) bv[nf] = bias[wq * 64 + nf * 16 + lr];
    }
#pragma unroll
    for (int m = 0; m < 4; ++m)
#pragma unroll
        for (int nf = 0; nf < 4; ++nf) {
            int c = wq * 64 + nf * 16 + lr;
#pragma unroll
            for (int reg = 0; reg < 4; ++reg) {
                float v = acc[m][nf][reg] + bv[nf];
                if (ACT) {
                    float e = __expf(-v);
                    v = v * __builtin_amdgcn_rcpf(1.f + e);
                }
                int r = m * 16 + lh * 4 + reg;
                short hb, lb;
                split_trunc(v, hb, lb);
                int off = r * 256 + (((c >> 3) ^ (r & 7)) * 8) + (c & 7);
                AH[off] = hb;
                AL[off] = lb;
            }
        }
}

__global__ __launch_bounds__(256, 2) void node_mlp_mfma(
    const float* __restrict__ h,
    const short* __restrict__ Wup_pk, const short* __restrict__ W1_pk,
    const short* __restrict__ W2_pk, const short* __restrict__ W3_pk,
    const float* __restrict__ b1, const float* __restrict__ b2,
    const float* __restrict__ b3, const float* __restrict__ W_out,
    float* __restrict__ out, int nn) {
    __shared__ short AH[64 * 256];
    __shared__ short AL[64 * 256];
    __shared__ float Bpart[64 * 4];

    const int tid = threadIdx.x;
    const int lane = tid & 63, wq = tid >> 6;
    const int lr = lane & 15, lh = lane >> 4;
    const int node0 = blockIdx.x * 64;

    // Stage h tile (64 x 64 f32) -> hi/lo bf16, swizzled, cols 0..63.
#pragma unroll
    for (int i = 0; i < 4; ++i) {
        int idx4 = tid + i * 256;
        int r = idx4 >> 4, c4 = idx4 & 15;
        float4 v = {0.f, 0.f, 0.f, 0.f};
        if (node0 + r < nn)
            v = *(const float4*)(h + (size_t)(node0 + r) * EDGE_DIM + c4 * 4);
        short h0, h1, h2, h3, l0, l1, l2, l3;
        split_trunc(v.x, h0, l0);
        split_trunc(v.y, h1, l1);
        split_trunc(v.z, h2, l2);
        split_trunc(v.w, h3, l3);
        int off = r * 256 + (((c4 >> 1) ^ (r & 7)) * 8) + (c4 & 1) * 4;
        uint2 hw, lw;
        hw.x = (unsigned short)h0 | ((unsigned)(unsigned short)h1 << 16);
        hw.y = (unsigned short)h2 | ((unsigned)(unsigned short)h3 << 16);
        lw.x = (unsigned short)l0 | ((unsigned)(unsigned short)l1 << 16);
        lw.y = (unsigned short)l2 | ((unsigned)(unsigned short)l3 << 16);
        *(uint2*)(AH + off) = hw;
        *(uint2*)(AL + off) = lw;
    }
    __syncthreads();

    f32x4 acc[4][4];

#pragma unroll
    for (int m = 0; m < 4; ++m)
#pragma unroll
        for (int n = 0; n < 4; ++n) acc[m][n] = (f32x4){0.f, 0.f, 0.f, 0.f};
    mm_layer<2>(AH, AL, Wup_pk, lr, lh, lane, wq, acc);
    __syncthreads();
    epilogue_store<false>(acc, AH, AL, nullptr, lr, lh, wq);
    __syncthreads();

#pragma unroll
    for (int m = 0; m < 4; ++m)
#pragma unroll
        for (int n = 0; n < 4; ++n) acc[m][n] = (f32x4){0.f, 0.f, 0.f, 0.f};
    mm_layer<8>(AH, AL, W1_pk, lr, lh, lane, wq, acc);
    __syncthreads();
    epilogue_store<true>(acc, AH, AL, b1, lr, lh, wq);
    __syncthreads();

#pragma unroll
    for (int m = 0; m < 4; ++m)
#pragma unroll
        for (int n = 0; n < 4; ++n) acc[m][n] = (f32x4){0.f, 0.f, 0.f, 0.f};
    mm_layer<8>(AH, AL, W2_pk, lr, lh, lane, wq, acc);
    __syncthreads();
    epilogue_store<true>(acc, AH, AL, b2, lr, lh, wq);
    __syncthreads();

#pragma unroll
    for (int m = 0; m < 4; ++m)
#pragma unroll
        for (int n = 0; n < 4; ++n) acc[m][n] = (f32x4){0.f, 0.f, 0.f, 0.f};
    mm_layer<8>(AH, AL, W3_pk, lr, lh, lane, wq, acc);

    float b3v[4], wo[4];
#pragma unroll
    for (int nf = 0; nf < 4; ++nf) {
        int c = wq * 64 + nf * 16 + lr;
        b3v[nf] = b3[c];
        wo[nf] = W_out[c];
    }
#pragma unroll
    for (int m = 0; m < 4; ++m) {
#pragma unroll
        for (int reg = 0; reg < 4; ++reg) {
            float s = 0.f;
#pragma unroll
            for (int nf = 0; nf < 4; ++nf) {
                float v = acc[m][nf][reg] + b3v[nf];
                float e = __expf(-v);
                v = v * __builtin_amdgcn_rcpf(1.f + e);
                s = fmaf(v, wo[nf], s);
            }
            s += __shfl_xor(s, 1);
            s += __shfl_xor(s, 2);
            s += __shfl_xor(s, 4);
            s += __shfl_xor(s, 8);
            if (lr == 0) Bpart[(m * 16 + lh * 4 + reg) * 4 + wq] = s;
        }
    }
    __syncthreads();
    if (tid < 64) {
        float s = Bpart[tid * 4] + Bpart[tid * 4 + 1] + Bpart[tid * 4 + 2] +
                  Bpart[tid * 4 + 3];
        if (node0 + tid < nn) out[node0 + tid] = s;
    }
}

// ---------------------------------------------------------------------------
extern "C" void kernel_launch(void* const* d_in, const int* in_sizes, int n_in,
                              void* d_out, int out_size, void* d_ws, size_t ws_size,
                              hipStream_t stream) {
    const float* x     = (const float*)d_in[0];
    const float* rbf   = (const float*)d_in[1];
    const void*  idx   = d_in[2];
    const float* W_rbf = (const float*)d_in[4];
    const float* W_up  = (const float*)d_in[5];
    const float* W1    = (const float*)d_in[6];
    const float* b1    = (const float*)d_in[7];
    const float* W2    = (const float*)d_in[8];
    const float* b2    = (const float*)d_in[9];
    const float* W3    = (const float*)d_in[10];
    const float* b3    = (const float*)d_in[11];
    const float* W_out = (const float*)d_in[12];
    float* out = (float*)d_out;

    const int n_edge = in_sizes[0] / EDGE_DIM;
    const int nn = out_size;

    // Workspace layout
    char* p = (char*)d_ws;
    float* h = (float*)p;            p += (size_t)nn * EDGE_DIM * sizeof(float);
    short* wup_pk = (short*)p;       p += 32 * 1024 * sizeof(short);
    short* w1_pk = (short*)p;        p += 128 * 1024 * sizeof(short);
    short* w2_pk = (short*)p;        p += 128 * 1024 * sizeof(short);
    short* w3_pk = (short*)p;        p += 128 * 1024 * sizeof(short);
    int* count = (int*)p;            p += (size_t)nn * sizeof(int);
    int* base = (int*)p;             p += (size_t)(nn + 1) * sizeof(int);
    int* cursor = (int*)p;           p += (size_t)nn * sizeof(int);
    int* partial = (int*)p;          p += 1024;
    int* order = (int*)p;

    const int nblk_scan = (nn + 1023) / 1024;

    hipMemsetAsync(count, 0, (size_t)nn * sizeof(int), stream);
    pack_all_kernel<<<104, 256, 0, stream>>>(W_up, W1, W2, W3, wup_pk, w1_pk,
                                             w2_pk, w3_pk);
    count_kernel<<<2048, 256, 0, stream>>>(idx, n_edge, nn, count);
    scan_a<<<nblk_scan, 256, 0, stream>>>(count, base, partial, nn);
    scan_b<<<1, 256, 0, stream>>>(partial, nblk_scan);
    scan_c<<<nblk_scan, 256, 0, stream>>>(base, cursor, partial, nn, n_edge);
    fill_order_kernel<<<2048, 256, 0, stream>>>(idx, n_edge, nn, cursor,
                                                order);
    gather_kernel<<<4096, 256, 0, stream>>>(x, rbf, order, base, W_rbf, h, nn);

    const int nb = (nn + 63) / 64;
    node_mlp_mfma<<<nb, 256, 0, stream>>>(h, wup_pk, w1_pk, w2_pk, w3_pk,
                                          b1, b2, b3, W_out, out, nn);
}

// Round 12
// 356.055 us; speedup vs baseline: 1.4298x; 1.0383x over previous
//
#include <hip/hip_runtime.h>
#include <hip/hip_bf16.h>

#define EDGE_DIM 64
#define UPD 256

typedef __attribute__((ext_vector_type(8))) short bf16x8;
typedef __attribute__((ext_vector_type(4))) float f32x4;

__device__ __forceinline__ short f2bf(float v) {
    __hip_bfloat16 b = __float2bfloat16(v);
    return *(short*)&b;
}
__device__ __forceinline__ float bf2f(short s) {
    __hip_bfloat16 b = *(__hip_bfloat16*)&s;
    return __bfloat162float(b);
}

// Truncation hi/lo split (cheap, ~5 VALU ops).
__device__ __forceinline__ void split_trunc(float v, short& hi, short& lo) {
    unsigned u = __float_as_uint(v);
    unsigned hu = u & 0xFFFF0000u;
    hi = (short)(hu >> 16);
    float rem = v - __uint_as_float(hu);
    lo = (short)(__float_as_uint(rem) >> 16);
}

// ---------------------------------------------------------------------------
// Per-block idx-dtype detection (deterministic across blocks).
// ---------------------------------------------------------------------------
__device__ __forceinline__ int detect_use64_block(const void* idx_v,
                                                  int n_edge, int nn,
                                                  int* bad_s) {
    if (threadIdx.x == 0) *bad_s = 0;
    __syncthreads();
    const long long* p = (const long long*)idx_v;
    int i = threadIdx.x;
    if (i < 256 && i < n_edge) {
        long long v = p[i];
        if (v < 0 || v >= (long long)nn) *bad_s = 1;  // benign race
    }
    __syncthreads();
    return !(*bad_s);
}

// ---------------------------------------------------------------------------
// Counting sort phase A: per-node histogram.
// ---------------------------------------------------------------------------
__global__ __launch_bounds__(256) void count_kernel(
    const void* __restrict__ idx_v, int n_edge, int nn,
    int* __restrict__ count) {
    __shared__ int bad_s;
    const int use64 = detect_use64_block(idx_v, n_edge, nn, &bad_s);
    const long long* i64 = (const long long*)idx_v;
    const int* i32 = (const int*)idx_v;
    for (int e = blockIdx.x * blockDim.x + threadIdx.x; e < n_edge;
         e += gridDim.x * blockDim.x) {
        int n = use64 ? (int)i64[e] : i32[e];
        atomicAdd(&count[n], 1);
    }
}

// ---------------------------------------------------------------------------
// Exclusive scan over count[nn] -> base[nn+1]  (3 kernels).
// ---------------------------------------------------------------------------
__global__ __launch_bounds__(256) void scan_a(const int* __restrict__ count,
                                              int* __restrict__ base,
                                              int* __restrict__ partial,
                                              int nn) {
    __shared__ int s[256];
    const int tid = threadIdx.x;
    const int i0 = blockIdx.x * 1024 + tid * 4;
    int c[4], tsum = 0;
#pragma unroll
    for (int j = 0; j < 4; ++j) {
        c[j] = (i0 + j < nn) ? count[i0 + j] : 0;
        tsum += c[j];
    }
    s[tid] = tsum;
    __syncthreads();
    for (int off = 1; off < 256; off <<= 1) {
        int v = (tid >= off) ? s[tid - off] : 0;
        __syncthreads();
        s[tid] += v;
        __syncthreads();
    }
    int run = s[tid] - tsum;
    if (tid == 255) partial[blockIdx.x] = s[255];
#pragma unroll
    for (int j = 0; j < 4; ++j) {
        if (i0 + j < nn) base[i0 + j] = run;
        run += c[j];
    }
}

__global__ __launch_bounds__(256) void scan_b(int* __restrict__ partial,
                                              int nblk) {
    __shared__ int s[256];
    const int tid = threadIdx.x;
    int v = (tid < nblk) ? partial[tid] : 0;
    s[tid] = v;
    __syncthreads();
    for (int off = 1; off < 256; off <<= 1) {
        int u = (tid >= off) ? s[tid - off] : 0;
        __syncthreads();
        s[tid] += u;
        __syncthreads();
    }
    if (tid < nblk) partial[tid] = s[tid] - v;
}

__global__ __launch_bounds__(256) void scan_c(int* __restrict__ base,
                                              int* __restrict__ cursor,
                                              const int* __restrict__ partial,
                                              int nn, int n_edge) {
    const int tid = threadIdx.x;
    const int b = blockIdx.x;
    const int add = partial[b];
    const int i0 = b * 1024 + tid * 4;
#pragma unroll
    for (int j = 0; j < 4; ++j) {
        int i = i0 + j;
        if (i < nn) {
            int v = base[i] + add;
            base[i] = v;
            cursor[i] = v;
        }
    }
    if (b == 0 && tid == 0) base[nn] = n_edge;
}

// ---------------------------------------------------------------------------
// Phase B: scatter edge ids + node ids into node-sorted slot order.
// ---------------------------------------------------------------------------
__global__ __launch_bounds__(256) void fill_order_kernel(
    const void* __restrict__ idx_v, int n_edge, int nn,
    int* __restrict__ cursor, int* __restrict__ order,
    int* __restrict__ nodeof) {
    __shared__ int bad_s;
    const int use64 = detect_use64_block(idx_v, n_edge, nn, &bad_s);
    const long long* i64 = (const long long*)idx_v;
    const int* i32 = (const int*)idx_v;
    for (int e = blockIdx.x * blockDim.x + threadIdx.x; e < n_edge;
         e += gridDim.x * blockDim.x) {
        int n = use64 ? (int)i64[e] : i32[e];
        int p = atomicAdd(&cursor[n], 1);
        order[p] = e;
        nodeof[p] = n;
    }
}

// ---------------------------------------------------------------------------
// Phase C v2: ALL-VECTOR-PATH segmented sum. Wave owns 64 consecutive slots.
// order/nodeof: per-lane vector loads (vmcnt). Edge id -> SGPR via
// v_readlane (SALU). x row: vector load, SGPR base. rbf: PER-LANE vector
// load (1 VGPR/edge); gate dot via 16 readlane + 16 fma. No scalar-memory
// (lgkmcnt) op anywhere in the loop -> counted-vmcnt pipelining, 16-deep.
// ---------------------------------------------------------------------------
__global__ __launch_bounds__(256) void segsum2_kernel(
    const float* __restrict__ x, const float* __restrict__ rbf,
    const int* __restrict__ order, const int* __restrict__ nodeof,
    const float* __restrict__ Wrbf, float* __restrict__ h, int n_edge) {
    const int lane = threadIdx.x & 63;
    float wreg[16];
#pragma unroll
    for (int q = 0; q < 16; ++q) wreg[q] = Wrbf[q * EDGE_DIM + lane];

    const int wid = threadIdx.x >> 6;
    const int nchunks = (n_edge + 63) >> 6;
    const int stride = gridDim.x * 4;

    for (int c = blockIdx.x * 4 + wid; c < nchunks; c += stride) {
        const int s0 = c * 64;
        int slot = s0 + lane;
        if (slot >= n_edge) slot = n_edge - 1;  // clamp (tail only)
        const int ev = order[slot];             // per-lane vector load
        const int ndv = nodeof[slot];           // per-lane vector load

        float acc = 0.f;
        int cur = -1;
#pragma unroll
        for (int g = 0; g < 4; ++g) {
            const int j0 = g * 16;
            // --- issue phase: 16 edges of loads, all independent ---
            int e[16];
            float xv[16], rv[16];
#pragma unroll
            for (int j = 0; j < 16; ++j) {
                e[j] = __builtin_amdgcn_readlane(ev, j0 + j);  // SGPR
                xv[j] = x[(size_t)e[j] * EDGE_DIM + lane];
                rv[j] = rbf[(size_t)e[j] * 16 + (lane & 15)];
            }
            // --- consume phase ---
#pragma unroll
            for (int j = 0; j < 16; ++j) {
                float gate = 0.f;
#pragma unroll
                for (int q = 0; q < 16; ++q) {
                    int rb = __builtin_amdgcn_readlane(
                        __float_as_int(rv[j]), q);
                    gate = fmaf(__int_as_float(rb), wreg[q], gate);
                }
                const int nd = __builtin_amdgcn_readlane(ndv, j0 + j);
                if (s0 + j0 + j < n_edge) {  // wave-uniform guard
                    if (nd != cur) {
                        if (cur >= 0)
                            atomicAdd(&h[(size_t)cur * EDGE_DIM + lane], acc);
                        cur = nd;
                        acc = 0.f;
                    }
                    acc = fmaf(gate, xv[j], acc);
                }
            }
        }
        if (cur >= 0) atomicAdd(&h[(size_t)cur * EDGE_DIM + lane], acc);
    }
}

// ---------------------------------------------------------------------------
// Pack all 4 weight matrices into MFMA-fragment bf16 hi/lo order.
// ---------------------------------------------------------------------------
__device__ __forceinline__ void pack_body(const float* __restrict__ W,
                                          short* __restrict__ out, int t) {
    int l = t & 63, f = t >> 6;
    int kt = f >> 4, nt = f & 15;
    int kbase = kt * 32 + (l >> 4) * 8;
    int col = nt * 16 + (l & 15);
#pragma unroll
    for (int j = 0; j < 8; ++j) {
        float v = W[(kbase + j) * UPD + col];
        short hb = f2bf(v);
        short lb = f2bf(v - bf2f(hb));
        out[f * 1024 + l * 8 + j] = hb;
        out[f * 1024 + 512 + l * 8 + j] = lb;
    }
}

__global__ __launch_bounds__(256) void pack_all_kernel(
    const float* __restrict__ Wup, const float* __restrict__ W1,
    const float* __restrict__ W2, const float* __restrict__ W3,
    short* __restrict__ oup, short* __restrict__ o1, short* __restrict__ o2,
    short* __restrict__ o3) {
    const int b = blockIdx.x;
    if (b < 8) {
        pack_body(Wup, oup, b * 256 + threadIdx.x);
    } else if (b < 40) {
        pack_body(W1, o1, (b - 8) * 256 + threadIdx.x);
    } else if (b < 72) {
        pack_body(W2, o2, (b - 40) * 256 + threadIdx.x);
    } else {
        pack_body(W3, o3, (b - 72) * 256 + threadIdx.x);
    }
}

// ---------------------------------------------------------------------------
// MFMA node MLP (R11 version: B-prefetch, trunc split, cheap SiLU).
// ---------------------------------------------------------------------------
template <int NK>
__device__ __forceinline__ void mm_layer(const short* AH, const short* AL,
                                         const short* __restrict__ Wpk,
                                         int lr, int lh, int lane, int wq,
                                         f32x4 acc[4][4]) {
    bf16x8 bc[4][2];
#pragma unroll
    for (int nf = 0; nf < 4; ++nf) {
        const short* p = Wpk + (wq * 4 + nf) * 1024 + lane * 8;
        bc[nf][0] = *(const bf16x8*)(p);
        bc[nf][1] = *(const bf16x8*)(p + 512);
    }
#pragma unroll
    for (int kt = 0; kt < NK; ++kt) {
        bf16x8 a[4][2];
#pragma unroll
        for (int m = 0; m < 4; ++m) {
            int r = m * 16 + lr;
            int ch = (kt * 4 + lh) ^ (r & 7);
            int off = r * 256 + ch * 8;  // shorts
            a[m][0] = *(const bf16x8*)(AH + off);
            a[m][1] = *(const bf16x8*)(AL + off);
        }
        bf16x8 bn[4][2];
        if (kt + 1 < NK) {
#pragma unroll
            for (int nf = 0; nf < 4; ++nf) {
                const short* p =
                    Wpk + ((kt + 1) * 16 + wq * 4 + nf) * 1024 + lane * 8;
                bn[nf][0] = *(const bf16x8*)(p);
                bn[nf][1] = *(const bf16x8*)(p + 512);
            }
        }
#pragma unroll
        for (int m = 0; m < 4; ++m)
#pragma unroll
            for (int nf = 0; nf < 4; ++nf)
                acc[m][nf] = __builtin_amdgcn_mfma_f32_16x16x32_bf16(
                    a[m][0], bc[nf][0], acc[m][nf], 0, 0, 0);
#pragma unroll
        for (int m = 0; m < 4; ++m)
#pragma unroll
            for (int nf = 0; nf < 4; ++nf)
                acc[m][nf] = __builtin_amdgcn_mfma_f32_16x16x32_bf16(
                    a[m][0], bc[nf][1], acc[m][nf], 0, 0, 0);
#pragma unroll
        for (int m = 0; m < 4; ++m)
#pragma unroll
            for (int nf = 0; nf < 4; ++nf)
                acc[m][nf] = __builtin_amdgcn_mfma_f32_16x16x32_bf16(
                    a[m][1], bc[nf][0], acc[m][nf], 0, 0, 0);
        if (kt + 1 < NK) {
#pragma unroll
            for (int nf = 0; nf < 4; ++nf) {
                bc[nf][0] = bn[nf][0];
                bc[nf][1] = bn[nf][1];
            }
        }
    }
}

template <bool ACT>
__device__ __forceinline__ void epilogue_store(f32x4 acc[4][4], short* AH,
                                               short* AL,
                                               const float* __restrict__ bias,
                                               int lr, int lh, int wq) {
    float bv[4] = {0.f, 0.f, 0.f, 0.f};
    if (bias) {
#pragma unroll
        for (int nf = 0; nf < 4; ++nf) bv[nf] = bias[wq * 64 + nf * 16 + lr];
    }
#pragma unroll
    for (int m = 0; m < 4; ++m)
#pragma unroll
        for (int nf = 0; nf < 4; ++nf) {
            int c = wq * 64 + nf * 16 + lr;
#pragma unroll
            for (int reg = 0; reg < 4; ++reg) {
                float v = acc[m][nf][reg] + bv[nf];
                if (ACT) {
                    float e = __expf(-v);
                    v = v * __builtin_amdgcn_rcpf(1.f + e);
                }
                int r = m * 16 + lh * 4 + reg;
                short hb, lb;
                split_trunc(v, hb, lb);
                int off = r * 256 + (((c >> 3) ^ (r & 7)) * 8) + (c & 7);
                AH[off] = hb;
                AL[off] = lb;
            }
        }
}

__global__ __launch_bounds__(256, 2) void node_mlp_mfma(
    const float* __restrict__ h,
    const short* __restrict__ Wup_pk, const short* __restrict__ W1_pk,
    const short* __restrict__ W2_pk, const short* __restrict__ W3_pk,
    const float* __restrict__ b1, const float* __restrict__ b2,
    const float* __restrict__ b3, const float* __restrict__ W_out,
    float* __restrict__ out, int nn) {
    __shared__ short AH[64 * 256];
    __shared__ short AL[64 * 256];
    __shared__ float Bpart[64 * 4];

    const int tid = threadIdx.x;
    const int lane = tid & 63, wq = tid >> 6;
    const int lr = lane & 15, lh = lane >> 4;
    const int node0 = blockIdx.x * 64;

#pragma unroll
    for (int i = 0; i < 4; ++i) {
        int idx4 = tid + i * 256;
        int r = idx4 >> 4, c4 = idx4 & 15;
        float4 v = {0.f, 0.f, 0.f, 0.f};
        if (node0 + r < nn)
            v = *(const float4*)(h + (size_t)(node0 + r) * EDGE_DIM + c4 * 4);
        short h0, h1, h2, h3, l0, l1, l2, l3;
        split_trunc(v.x, h0, l0);
        split_trunc(v.y, h1, l1);
        split_trunc(v.z, h2, l2);
        split_trunc(v.w, h3, l3);
        int off = r * 256 + (((c4 >> 1) ^ (r & 7)) * 8) + (c4 & 1) * 4;
        uint2 hw, lw;
        hw.x = (unsigned short)h0 | ((unsigned)(unsigned short)h1 << 16);
        hw.y = (unsigned short)h2 | ((unsigned)(unsigned short)h3 << 16);
        lw.x = (unsigned short)l0 | ((unsigned)(unsigned short)l1 << 16);
        lw.y = (unsigned short)l2 | ((unsigned)(unsigned short)l3 << 16);
        *(uint2*)(AH + off) = hw;
        *(uint2*)(AL + off) = lw;
    }
    __syncthreads();

    f32x4 acc[4][4];

#pragma unroll
    for (int m = 0; m < 4; ++m)
#pragma unroll
        for (int n = 0; n < 4; ++n) acc[m][n] = (f32x4){0.f, 0.f, 0.f, 0.f};
    mm_layer<2>(AH, AL, Wup_pk, lr, lh, lane, wq, acc);
    __syncthreads();
    epilogue_store<false>(acc, AH, AL, nullptr, lr, lh, wq);
    __syncthreads();

#pragma unroll
    for (int m = 0; m < 4; ++m)
#pragma unroll
        for (int n = 0; n < 4; ++n) acc[m][n] = (f32x4){0.f, 0.f, 0.f, 0.f};
    mm_layer<8>(AH, AL, W1_pk, lr, lh, lane, wq, acc);
    __syncthreads();
    epilogue_store<true>(acc, AH, AL, b1, lr, lh, wq);
    __syncthreads();

#pragma unroll
    for (int m = 0; m < 4; ++m)
#pragma unroll
        for (int n = 0; n < 4; ++n) acc[m][n] = (f32x4){0.f, 0.f, 0.f, 0.f};
    mm_layer<8>(AH, AL, W2_pk, lr, lh, lane, wq, acc);
    __syncthreads();
    epilogue_store<true>(acc, AH, AL, b2, lr, lh, wq);
    __syncthreads();

#pragma unroll
    for (int m = 0; m < 4; ++m)
#pragma unroll
        for (int n = 0; n < 4; ++n) acc[m][n] = (f32x4){0.f, 0.f, 0.f, 0.f};
    mm_layer<8>(AH, AL, W3_pk, lr, lh, lane, wq, acc);

    float b3v[4], wo[4];
#pragma unroll
    for (int nf = 0; nf < 4; ++nf) {
        int c = wq * 64 + nf * 16 + lr;
        b3v[nf] = b3[c];
        wo[nf] = W_out[c];
    }
#pragma unroll
    for (int m = 0; m < 4; ++m) {
#pragma unroll
        for (int reg = 0; reg < 4; ++reg) {
            float s = 0.f;
#pragma unroll
            for (int nf = 0; nf < 4; ++nf) {
                float v = acc[m][nf][reg] + b3v[nf];
                float e = __expf(-v);
                v = v * __builtin_amdgcn_rcpf(1.f + e);
                s = fmaf(v, wo[nf], s);
            }
            s += __shfl_xor(s, 1);
            s += __shfl_xor(s, 2);
            s += __shfl_xor(s, 4);
            s += __shfl_xor(s, 8);
            if (lr == 0) Bpart[(m * 16 + lh * 4 + reg) * 4 + wq] = s;
        }
    }
    __syncthreads();
    if (tid < 64) {
        float s = Bpart[tid * 4] + Bpart[tid * 4 + 1] + Bpart[tid * 4 + 2] +
                  Bpart[tid * 4 + 3];
        if (node0 + tid < nn) out[node0 + tid] = s;
    }
}

// ---------------------------------------------------------------------------
extern "C" void kernel_launch(void* const* d_in, const int* in_sizes, int n_in,
                              void* d_out, int out_size, void* d_ws, size_t ws_size,
                              hipStream_t stream) {
    const float* x     = (const float*)d_in[0];
    const float* rbf   = (const float*)d_in[1];
    const void*  idx   = d_in[2];
    const float* W_rbf = (const float*)d_in[4];
    const float* W_up  = (const float*)d_in[5];
    const float* W1    = (const float*)d_in[6];
    const float* b1    = (const float*)d_in[7];
    const float* W2    = (const float*)d_in[8];
    const float* b2    = (const float*)d_in[9];
    const float* W3    = (const float*)d_in[10];
    const float* b3    = (const float*)d_in[11];
    const float* W_out = (const float*)d_in[12];
    float* out = (float*)d_out;

    const int n_edge = in_sizes[0] / EDGE_DIM;
    const int nn = out_size;

    // Workspace layout
    char* p = (char*)d_ws;
    float* h = (float*)p;            p += (size_t)nn * EDGE_DIM * sizeof(float);
    short* wup_pk = (short*)p;       p += 32 * 1024 * sizeof(short);
    short* w1_pk = (short*)p;        p += 128 * 1024 * sizeof(short);
    short* w2_pk = (short*)p;        p += 128 * 1024 * sizeof(short);
    short* w3_pk = (short*)p;        p += 128 * 1024 * sizeof(short);
    int* count = (int*)p;            p += (size_t)nn * sizeof(int);
    int* base = (int*)p;             p += (size_t)(nn + 1) * sizeof(int);
    int* cursor = (int*)p;           p += (size_t)nn * sizeof(int);
    int* partial = (int*)p;          p += 1024;
    int* order = (int*)p;            p += (size_t)n_edge * sizeof(int);
    int* nodeof = (int*)p;

    const int nblk_scan = (nn + 1023) / 1024;

    hipMemsetAsync(h, 0, (size_t)nn * EDGE_DIM * sizeof(float), stream);
    hipMemsetAsync(count, 0, (size_t)nn * sizeof(int), stream);
    pack_all_kernel<<<104, 256, 0, stream>>>(W_up, W1, W2, W3, wup_pk, w1_pk,
                                             w2_pk, w3_pk);
    count_kernel<<<2048, 256, 0, stream>>>(idx, n_edge, nn, count);
    scan_a<<<nblk_scan, 256, 0, stream>>>(count, base, partial, nn);
    scan_b<<<1, 256, 0, stream>>>(partial, nblk_scan);
    scan_c<<<nblk_scan, 256, 0, stream>>>(base, cursor, partial, nn, n_edge);
    fill_order_kernel<<<2048, 256, 0, stream>>>(idx, n_edge, nn, cursor,
                                                order, nodeof);
    const int nchunks = (n_edge + 63) / 64;
    const int nblk_seg = (nchunks + 3) / 4;
    segsum2_kernel<<<nblk_seg, 256, 0, stream>>>(x, rbf, order, nodeof,
                                                 W_rbf, h, n_edge);

    const int nb = (nn + 63) / 64;
    node_mlp_mfma<<<nb, 256, 0, stream>>>(h, wup_pk, w1_pk, w2_pk, w3_pk,
                                          b1, b2, b3, W_out, out, nn);
}

// Round 13
// 352.932 us; speedup vs baseline: 1.4424x; 1.0088x over previous
//
#include <hip/hip_runtime.h>
#include <hip/hip_bf16.h>

#define EDGE_DIM 64
#define UPD 256

typedef __attribute__((ext_vector_type(8))) short bf16x8;
typedef __attribute__((ext_vector_type(4))) float f32x4;

__device__ __forceinline__ short f2bf(float v) {
    __hip_bfloat16 b = __float2bfloat16(v);
    return *(short*)&b;
}
__device__ __forceinline__ float bf2f(short s) {
    __hip_bfloat16 b = *(__hip_bfloat16*)&s;
    return __bfloat162float(b);
}

// Truncation hi/lo split (cheap, ~5 VALU ops).
__device__ __forceinline__ void split_trunc(float v, short& hi, short& lo) {
    unsigned u = __float_as_uint(v);
    unsigned hu = u & 0xFFFF0000u;
    hi = (short)(hu >> 16);
    float rem = v - __uint_as_float(hu);
    lo = (short)(__float_as_uint(rem) >> 16);
}

// ---------------------------------------------------------------------------
// Workspace zeroing: h (float4-wide) + count, one launch, full-BW grid.
// Replaces hipMemsetAsync whose rocclr fill kernel ran at 10% occupancy
// (~145us for 25.6MB; this takes ~6us).
// ---------------------------------------------------------------------------
__global__ __launch_bounds__(256) void zero_ws_kernel(
    float4* __restrict__ h4, long long n4, int* __restrict__ count, int nn) {
    const long long t = (long long)blockIdx.x * blockDim.x + threadIdx.x;
    const long long stride = (long long)gridDim.x * blockDim.x;
    const float4 z = {0.f, 0.f, 0.f, 0.f};
    for (long long i = t; i < n4; i += stride) h4[i] = z;
    for (long long i = t; i < nn; i += stride) count[i] = 0;
}

// ---------------------------------------------------------------------------
// Per-block idx-dtype detection (deterministic across blocks).
// ---------------------------------------------------------------------------
__device__ __forceinline__ int detect_use64_block(const void* idx_v,
                                                  int n_edge, int nn,
                                                  int* bad_s) {
    if (threadIdx.x == 0) *bad_s = 0;
    __syncthreads();
    const long long* p = (const long long*)idx_v;
    int i = threadIdx.x;
    if (i < 256 && i < n_edge) {
        long long v = p[i];
        if (v < 0 || v >= (long long)nn) *bad_s = 1;  // benign race
    }
    __syncthreads();
    return !(*bad_s);
}

// ---------------------------------------------------------------------------
// Counting sort phase A: per-node histogram.
// ---------------------------------------------------------------------------
__global__ __launch_bounds__(256) void count_kernel(
    const void* __restrict__ idx_v, int n_edge, int nn,
    int* __restrict__ count) {
    __shared__ int bad_s;
    const int use64 = detect_use64_block(idx_v, n_edge, nn, &bad_s);
    const long long* i64 = (const long long*)idx_v;
    const int* i32 = (const int*)idx_v;
    for (int e = blockIdx.x * blockDim.x + threadIdx.x; e < n_edge;
         e += gridDim.x * blockDim.x) {
        int n = use64 ? (int)i64[e] : i32[e];
        atomicAdd(&count[n], 1);
    }
}

// ---------------------------------------------------------------------------
// Exclusive scan over count[nn] -> base[nn+1]  (3 kernels).
// ---------------------------------------------------------------------------
__global__ __launch_bounds__(256) void scan_a(const int* __restrict__ count,
                                              int* __restrict__ base,
                                              int* __restrict__ partial,
                                              int nn) {
    __shared__ int s[256];
    const int tid = threadIdx.x;
    const int i0 = blockIdx.x * 1024 + tid * 4;
    int c[4], tsum = 0;
#pragma unroll
    for (int j = 0; j < 4; ++j) {
        c[j] = (i0 + j < nn) ? count[i0 + j] : 0;
        tsum += c[j];
    }
    s[tid] = tsum;
    __syncthreads();
    for (int off = 1; off < 256; off <<= 1) {
        int v = (tid >= off) ? s[tid - off] : 0;
        __syncthreads();
        s[tid] += v;
        __syncthreads();
    }
    int run = s[tid] - tsum;
    if (tid == 255) partial[blockIdx.x] = s[255];
#pragma unroll
    for (int j = 0; j < 4; ++j) {
        if (i0 + j < nn) base[i0 + j] = run;
        run += c[j];
    }
}

__global__ __launch_bounds__(256) void scan_b(int* __restrict__ partial,
                                              int nblk) {
    __shared__ int s[256];
    const int tid = threadIdx.x;
    int v = (tid < nblk) ? partial[tid] : 0;
    s[tid] = v;
    __syncthreads();
    for (int off = 1; off < 256; off <<= 1) {
        int u = (tid >= off) ? s[tid - off] : 0;
        __syncthreads();
        s[tid] += u;
        __syncthreads();
    }
    if (tid < nblk) partial[tid] = s[tid] - v;
}

__global__ __launch_bounds__(256) void scan_c(int* __restrict__ base,
                                              int* __restrict__ cursor,
                                              const int* __restrict__ partial,
                                              int nn, int n_edge) {
    const int tid = threadIdx.x;
    const int b = blockIdx.x;
    const int add = partial[b];
    const int i0 = b * 1024 + tid * 4;
#pragma unroll
    for (int j = 0; j < 4; ++j) {
        int i = i0 + j;
        if (i < nn) {
            int v = base[i] + add;
            base[i] = v;
            cursor[i] = v;
        }
    }
    if (b == 0 && tid == 0) base[nn] = n_edge;
}

// ---------------------------------------------------------------------------
// Phase B: scatter edge ids + node ids into node-sorted slot order.
// ---------------------------------------------------------------------------
__global__ __launch_bounds__(256) void fill_order_kernel(
    const void* __restrict__ idx_v, int n_edge, int nn,
    int* __restrict__ cursor, int* __restrict__ order,
    int* __restrict__ nodeof) {
    __shared__ int bad_s;
    const int use64 = detect_use64_block(idx_v, n_edge, nn, &bad_s);
    const long long* i64 = (const long long*)idx_v;
    const int* i32 = (const int*)idx_v;
    for (int e = blockIdx.x * blockDim.x + threadIdx.x; e < n_edge;
         e += gridDim.x * blockDim.x) {
        int n = use64 ? (int)i64[e] : i32[e];
        int p = atomicAdd(&cursor[n], 1);
        order[p] = e;
        nodeof[p] = n;
    }
}

// ---------------------------------------------------------------------------
// Phase C v2: ALL-VECTOR-PATH segmented sum (R12, proven <143us).
// ---------------------------------------------------------------------------
__global__ __launch_bounds__(256) void segsum2_kernel(
    const float* __restrict__ x, const float* __restrict__ rbf,
    const int* __restrict__ order, const int* __restrict__ nodeof,
    const float* __restrict__ Wrbf, float* __restrict__ h, int n_edge) {
    const int lane = threadIdx.x & 63;
    float wreg[16];
#pragma unroll
    for (int q = 0; q < 16; ++q) wreg[q] = Wrbf[q * EDGE_DIM + lane];

    const int wid = threadIdx.x >> 6;
    const int nchunks = (n_edge + 63) >> 6;
    const int stride = gridDim.x * 4;

    for (int c = blockIdx.x * 4 + wid; c < nchunks; c += stride) {
        const int s0 = c * 64;
        int slot = s0 + lane;
        if (slot >= n_edge) slot = n_edge - 1;  // clamp (tail only)
        const int ev = order[slot];             // per-lane vector load
        const int ndv = nodeof[slot];           // per-lane vector load

        float acc = 0.f;
        int cur = -1;
#pragma unroll
        for (int g = 0; g < 4; ++g) {
            const int j0 = g * 16;
            // --- issue phase: 16 edges of loads, all independent ---
            int e[16];
            float xv[16], rv[16];
#pragma unroll
            for (int j = 0; j < 16; ++j) {
                e[j] = __builtin_amdgcn_readlane(ev, j0 + j);  // SGPR
                xv[j] = x[(size_t)e[j] * EDGE_DIM + lane];
                rv[j] = rbf[(size_t)e[j] * 16 + (lane & 15)];
            }
            // --- consume phase ---
#pragma unroll
            for (int j = 0; j < 16; ++j) {
                float gate = 0.f;
#pragma unroll
                for (int q = 0; q < 16; ++q) {
                    int rb = __builtin_amdgcn_readlane(
                        __float_as_int(rv[j]), q);
                    gate = fmaf(__int_as_float(rb), wreg[q], gate);
                }
                const int nd = __builtin_amdgcn_readlane(ndv, j0 + j);
                if (s0 + j0 + j < n_edge) {  // wave-uniform guard
                    if (nd != cur) {
                        if (cur >= 0)
                            atomicAdd(&h[(size_t)cur * EDGE_DIM + lane], acc);
                        cur = nd;
                        acc = 0.f;
                    }
                    acc = fmaf(gate, xv[j], acc);
                }
            }
        }
        if (cur >= 0) atomicAdd(&h[(size_t)cur * EDGE_DIM + lane], acc);
    }
}

// ---------------------------------------------------------------------------
// Pack all 4 weight matrices into MFMA-fragment bf16 hi/lo order.
// ---------------------------------------------------------------------------
__device__ __forceinline__ void pack_body(const float* __restrict__ W,
                                          short* __restrict__ out, int t) {
    int l = t & 63, f = t >> 6;
    int kt = f >> 4, nt = f & 15;
    int kbase = kt * 32 + (l >> 4) * 8;
    int col = nt * 16 + (l & 15);
#pragma unroll
    for (int j = 0; j < 8; ++j) {
        float v = W[(kbase + j) * UPD + col];
        short hb = f2bf(v);
        short lb = f2bf(v - bf2f(hb));
        out[f * 1024 + l * 8 + j] = hb;
        out[f * 1024 + 512 + l * 8 + j] = lb;
    }
}

__global__ __launch_bounds__(256) void pack_all_kernel(
    const float* __restrict__ Wup, const float* __restrict__ W1,
    const float* __restrict__ W2, const float* __restrict__ W3,
    short* __restrict__ oup, short* __restrict__ o1, short* __restrict__ o2,
    short* __restrict__ o3) {
    const int b = blockIdx.x;
    if (b < 8) {
        pack_body(Wup, oup, b * 256 + threadIdx.x);
    } else if (b < 40) {
        pack_body(W1, o1, (b - 8) * 256 + threadIdx.x);
    } else if (b < 72) {
        pack_body(W2, o2, (b - 40) * 256 + threadIdx.x);
    } else {
        pack_body(W3, o3, (b - 72) * 256 + threadIdx.x);
    }
}

// ---------------------------------------------------------------------------
// MFMA node MLP (R11 version: B-prefetch, trunc split, cheap SiLU).
// ---------------------------------------------------------------------------
template <int NK>
__device__ __forceinline__ void mm_layer(const short* AH, const short* AL,
                                         const short* __restrict__ Wpk,
                                         int lr, int lh, int lane, int wq,
                                         f32x4 acc[4][4]) {
    bf16x8 bc[4][2];
#pragma unroll
    for (int nf = 0; nf < 4; ++nf) {
        const short* p = Wpk + (wq * 4 + nf) * 1024 + lane * 8;
        bc[nf][0] = *(const bf16x8*)(p);
        bc[nf][1] = *(const bf16x8*)(p + 512);
    }
#pragma unroll
    for (int kt = 0; kt < NK; ++kt) {
        bf16x8 a[4][2];
#pragma unroll
        for (int m = 0; m < 4; ++m) {
            int r = m * 16 + lr;
            int ch = (kt * 4 + lh) ^ (r & 7);
            int off = r * 256 + ch * 8;  // shorts
            a[m][0] = *(const bf16x8*)(AH + off);
            a[m][1] = *(const bf16x8*)(AL + off);
        }
        bf16x8 bn[4][2];
        if (kt + 1 < NK) {
#pragma unroll
            for (int nf = 0; nf < 4; ++nf) {
                const short* p =
                    Wpk + ((kt + 1) * 16 + wq * 4 + nf) * 1024 + lane * 8;
                bn[nf][0] = *(const bf16x8*)(p);
                bn[nf][1] = *(const bf16x8*)(p + 512);
            }
        }
#pragma unroll
        for (int m = 0; m < 4; ++m)
#pragma unroll
            for (int nf = 0; nf < 4; ++nf)
                acc[m][nf] = __builtin_amdgcn_mfma_f32_16x16x32_bf16(
                    a[m][0], bc[nf][0], acc[m][nf], 0, 0, 0);
#pragma unroll
        for (int m = 0; m < 4; ++m)
#pragma unroll
            for (int nf = 0; nf < 4; ++nf)
                acc[m][nf] = __builtin_amdgcn_mfma_f32_16x16x32_bf16(
                    a[m][0], bc[nf][1], acc[m][nf], 0, 0, 0);
#pragma unroll
        for (int m = 0; m < 4; ++m)
#pragma unroll
            for (int nf = 0; nf < 4; ++nf)
                acc[m][nf] = __builtin_amdgcn_mfma_f32_16x16x32_bf16(
                    a[m][1], bc[nf][0], acc[m][nf], 0, 0, 0);
        if (kt + 1 < NK) {
#pragma unroll
            for (int nf = 0; nf < 4; ++nf) {
                bc[nf][0] = bn[nf][0];
                bc[nf][1] = bn[nf][1];
            }
        }
    }
}

template <bool ACT>
__device__ __forceinline__ void epilogue_store(f32x4 acc[4][4], short* AH,
                                               short* AL,
                                               const float* __restrict__ bias,
                                               int lr, int lh, int wq) {
    float bv[4] = {0.f, 0.f, 0.f, 0.f};
    if (bias) {
#pragma unroll
        for (int nf = 0; nf < 4; ++nf) bv[nf] = bias[wq * 64 + nf * 16 + lr];
    }
#pragma unroll
    for (int m = 0; m < 4; ++m)
#pragma unroll
        for (int nf = 0; nf < 4; ++nf) {
            int c = wq * 64 + nf * 16 + lr;
#pragma unroll
            for (int reg = 0; reg < 4; ++reg) {
                float v = acc[m][nf][reg] + bv[nf];
                if (ACT) {
                    float e = __expf(-v);
                    v = v * __builtin_amdgcn_rcpf(1.f + e);
                }
                int r = m * 16 + lh * 4 + reg;
                short hb, lb;
                split_trunc(v, hb, lb);
                int off = r * 256 + (((c >> 3) ^ (r & 7)) * 8) + (c & 7);
                AH[off] = hb;
                AL[off] = lb;
            }
        }
}

__global__ __launch_bounds__(256, 2) void node_mlp_mfma(
    const float* __restrict__ h,
    const short* __restrict__ Wup_pk, const short* __restrict__ W1_pk,
    const short* __restrict__ W2_pk, const short* __restrict__ W3_pk,
    const float* __restrict__ b1, const float* __restrict__ b2,
    const float* __restrict__ b3, const float* __restrict__ W_out,
    float* __restrict__ out, int nn) {
    __shared__ short AH[64 * 256];
    __shared__ short AL[64 * 256];
    __shared__ float Bpart[64 * 4];

    const int tid = threadIdx.x;
    const int lane = tid & 63, wq = tid >> 6;
    const int lr = lane & 15, lh = lane >> 4;
    const int node0 = blockIdx.x * 64;

#pragma unroll
    for (int i = 0; i < 4; ++i) {
        int idx4 = tid + i * 256;
        int r = idx4 >> 4, c4 = idx4 & 15;
        float4 v = {0.f, 0.f, 0.f, 0.f};
        if (node0 + r < nn)
            v = *(const float4*)(h + (size_t)(node0 + r) * EDGE_DIM + c4 * 4);
        short h0, h1, h2, h3, l0, l1, l2, l3;
        split_trunc(v.x, h0, l0);
        split_trunc(v.y, h1, l1);
        split_trunc(v.z, h2, l2);
        split_trunc(v.w, h3, l3);
        int off = r * 256 + (((c4 >> 1) ^ (r & 7)) * 8) + (c4 & 1) * 4;
        uint2 hw, lw;
        hw.x = (unsigned short)h0 | ((unsigned)(unsigned short)h1 << 16);
        hw.y = (unsigned short)h2 | ((unsigned)(unsigned short)h3 << 16);
        lw.x = (unsigned short)l0 | ((unsigned)(unsigned short)l1 << 16);
        lw.y = (unsigned short)l2 | ((unsigned)(unsigned short)l3 << 16);
        *(uint2*)(AH + off) = hw;
        *(uint2*)(AL + off) = lw;
    }
    __syncthreads();

    f32x4 acc[4][4];

#pragma unroll
    for (int m = 0; m < 4; ++m)
#pragma unroll
        for (int n = 0; n < 4; ++n) acc[m][n] = (f32x4){0.f, 0.f, 0.f, 0.f};
    mm_layer<2>(AH, AL, Wup_pk, lr, lh, lane, wq, acc);
    __syncthreads();
    epilogue_store<false>(acc, AH, AL, nullptr, lr, lh, wq);
    __syncthreads();

#pragma unroll
    for (int m = 0; m < 4; ++m)
#pragma unroll
        for (int n = 0; n < 4; ++n) acc[m][n] = (f32x4){0.f, 0.f, 0.f, 0.f};
    mm_layer<8>(AH, AL, W1_pk, lr, lh, lane, wq, acc);
    __syncthreads();
    epilogue_store<true>(acc, AH, AL, b1, lr, lh, wq);
    __syncthreads();

#pragma unroll
    for (int m = 0; m < 4; ++m)
#pragma unroll
        for (int n = 0; n < 4; ++n) acc[m][n] = (f32x4){0.f, 0.f, 0.f, 0.f};
    mm_layer<8>(AH, AL, W2_pk, lr, lh, lane, wq, acc);
    __syncthreads();
    epilogue_store<true>(acc, AH, AL, b2, lr, lh, wq);
    __syncthreads();

#pragma unroll
    for (int m = 0; m < 4; ++m)
#pragma unroll
        for (int n = 0; n < 4; ++n) acc[m][n] = (f32x4){0.f, 0.f, 0.f, 0.f};
    mm_layer<8>(AH, AL, W3_pk, lr, lh, lane, wq, acc);

    float b3v[4], wo[4];
#pragma unroll
    for (int nf = 0; nf < 4; ++nf) {
        int c = wq * 64 + nf * 16 + lr;
        b3v[nf] = b3[c];
        wo[nf] = W_out[c];
    }
#pragma unroll
    for (int m = 0; m < 4; ++m) {
#pragma unroll
        for (int reg = 0; reg < 4; ++reg) {
            float s = 0.f;
#pragma unroll
            for (int nf = 0; nf < 4; ++nf) {
                float v = acc[m][nf][reg] + b3v[nf];
                float e = __expf(-v);
                v = v * __builtin_amdgcn_rcpf(1.f + e);
                s = fmaf(v, wo[nf], s);
            }
            s += __shfl_xor(s, 1);
            s += __shfl_xor(s, 2);
            s += __shfl_xor(s, 4);
            s += __shfl_xor(s, 8);
            if (lr == 0) Bpart[(m * 16 + lh * 4 + reg) * 4 + wq] = s;
        }
    }
    __syncthreads();
    if (tid < 64) {
        float s = Bpart[tid * 4] + Bpart[tid * 4 + 1] + Bpart[tid * 4 + 2] +
                  Bpart[tid * 4 + 3];
        if (node0 + tid < nn) out[node0 + tid] = s;
    }
}

// ---------------------------------------------------------------------------
extern "C" void kernel_launch(void* const* d_in, const int* in_sizes, int n_in,
                              void* d_out, int out_size, void* d_ws, size_t ws_size,
                              hipStream_t stream) {
    const float* x     = (const float*)d_in[0];
    const float* rbf   = (const float*)d_in[1];
    const void*  idx   = d_in[2];
    const float* W_rbf = (const float*)d_in[4];
    const float* W_up  = (const float*)d_in[5];
    const float* W1    = (const float*)d_in[6];
    const float* b1    = (const float*)d_in[7];
    const float* W2    = (const float*)d_in[8];
    const float* b2    = (const float*)d_in[9];
    const float* W3    = (const float*)d_in[10];
    const float* b3    = (const float*)d_in[11];
    const float* W_out = (const float*)d_in[12];
    float* out = (float*)d_out;

    const int n_edge = in_sizes[0] / EDGE_DIM;
    const int nn = out_size;

    // Workspace layout
    char* p = (char*)d_ws;
    float* h = (float*)p;            p += (size_t)nn * EDGE_DIM * sizeof(float);
    short* wup_pk = (short*)p;       p += 32 * 1024 * sizeof(short);
    short* w1_pk = (short*)p;        p += 128 * 1024 * sizeof(short);
    short* w2_pk = (short*)p;        p += 128 * 1024 * sizeof(short);
    short* w3_pk = (short*)p;        p += 128 * 1024 * sizeof(short);
    int* count = (int*)p;            p += (size_t)nn * sizeof(int);
    int* base = (int*)p;             p += (size_t)(nn + 1) * sizeof(int);
    int* cursor = (int*)p;           p += (size_t)nn * sizeof(int);
    int* partial = (int*)p;          p += 1024;
    int* order = (int*)p;            p += (size_t)n_edge * sizeof(int);
    int* nodeof = (int*)p;

    const int nblk_scan = (nn + 1023) / 1024;

    zero_ws_kernel<<<2048, 256, 0, stream>>>(
        (float4*)h, (long long)nn * EDGE_DIM / 4, count, nn);
    pack_all_kernel<<<104, 256, 0, stream>>>(W_up, W1, W2, W3, wup_pk, w1_pk,
                                             w2_pk, w3_pk);
    count_kernel<<<2048, 256, 0, stream>>>(idx, n_edge, nn, count);
    scan_a<<<nblk_scan, 256, 0, stream>>>(count, base, partial, nn);
    scan_b<<<1, 256, 0, stream>>>(partial, nblk_scan);
    scan_c<<<nblk_scan, 256, 0, stream>>>(base, cursor, partial, nn, n_edge);
    fill_order_kernel<<<2048, 256, 0, stream>>>(idx, n_edge, nn, cursor,
                                                order, nodeof);
    const int nchunks = (n_edge + 63) / 64;
    const int nblk_seg = (nchunks + 3) / 4;
    segsum2_kernel<<<nblk_seg, 256, 0, stream>>>(x, rbf, order, nodeof,
                                                 W_rbf, h, n_edge);

    const int nb = (nn + 63) / 64;
    node_mlp_mfma<<<nb, 256, 0, stream>>>(h, wup_pk, w1_pk, w2_pk, w3_pk,
                                          b1, b2, b3, W_out, out, nn);
}